// Round 1
// baseline (822.195 us; speedup 1.0000x reference)
//
#include <hip/hip_runtime.h>
#include <hip/hip_bf16.h>
#include <cstdint>

// Problem constants
#define NUM_FIELDS 26
#define VOCAB      100000
#define BATCH      16384
#define CK         416      // 415 (351 interactions + 64 dense_out) padded to 416
#define CS_STRIDE  424      // Cs leading dim (shorts); 848 B rows, 16B-aligned

typedef __attribute__((ext_vector_type(8)))  short bf16x8_t;
typedef __attribute__((ext_vector_type(16))) float f32x16_t;

__device__ __forceinline__ short f2bf(float x) {
  unsigned u = __builtin_bit_cast(unsigned, x);
  u += 0x7FFFu + ((u >> 16) & 1u);   // RNE; inputs finite
  return (short)(u >> 16);
}

// ---------------------------------------------------------------------------
// K0: block 0 -> piecewise-linear bottom-MLP table (exact fp32):
//   dense_out[d] = relu(price*P[seg][d] + Q[seg][d]), seg from bps[128].
// blocks 1..256 -> wt1t[n][k] = bf16(Wt1[k][n]), k padded 415->416 with 0.
// ---------------------------------------------------------------------------
__global__ __launch_bounds__(128) void k0_prep(
    const float* __restrict__ Wp, const float* __restrict__ bp,
    const float* __restrict__ W1, const float* __restrict__ b1,
    const float* __restrict__ W2, const float* __restrict__ b2,
    const float* __restrict__ Wt1,
    float* __restrict__ bps, float* __restrict__ PQ, short* __restrict__ wt1t) {
  if (blockIdx.x != 0) {
    const int n = blockIdx.x - 1;
    for (int k = threadIdx.x; k < CK; k += 128) {
      float v = (k < 415) ? Wt1[(size_t)k * 256 + n] : 0.f;
      wt1t[(size_t)n * CK + k] = f2bf(v);
    }
    return;
  }
  __shared__ float u1s[128], c1s[128], ts[128];
  __shared__ int ord[128];
  const int j = threadIdx.x;
  float u = 0.f, c = 0.f;
  for (int d = 0; d < 64; ++d) {
    float w = W1[d * 128 + j];
    u = fmaf(Wp[d], w, u);
    c = fmaf(bp[d], w, c);
  }
  c += b1[j];
  u1s[j] = u; c1s[j] = c;
  ts[j] = (u != 0.f) ? (-c / u) : __builtin_inff();
  __syncthreads();
  const float tj = ts[j];
  int r = 0;
  for (int i = 0; i < 128; ++i) {
    float ti = ts[i];
    if (ti < tj || (ti == tj && i < j)) ++r;
  }
  ord[r] = j;
  __syncthreads();
  bps[j] = ts[ord[j]];
  if (j < 64) {
    const int d = j;
    float P = 0.f, Q = b2[d];
    for (int k = 0; k < 128; ++k) {
      float uk = u1s[k];
      bool act = (uk < 0.f) || (uk == 0.f && c1s[k] > 0.f);
      if (act) {
        float w = W2[k * 64 + d];
        P = fmaf(uk, w, P);
        Q = fmaf(c1s[k], w, Q);
      }
    }
    PQ[d] = P; PQ[129 * 64 + d] = Q;
    for (int seg = 1; seg <= 128; ++seg) {
      int jk = ord[seg - 1];
      float uk = u1s[jk], ck = c1s[jk];
      float sgn = (uk > 0.f) ? 1.f : ((uk < 0.f) ? -1.f : 0.f);
      float w = W2[jk * 64 + d] * sgn;
      P = fmaf(uk, w, P);
      Q = fmaf(ck, w, Q);
      PQ[seg * 64 + d] = P;
      PQ[129 * 64 + seg * 64 + d] = Q;
    }
  }
}

// ---------------------------------------------------------------------------
// K1 (fused): 512 blocks x 512 threads; 32 samples/block.
// Phase 1 (rewritten): direct-layout gather. Lane (row=lane&31, kh=lane>>5)
//   loads its MFMA A-fragment for feature-row `row` straight from emb as
//   8x float4 at float offsets {16q+8kh, 16q+8kh+4}, converts to bf16 in
//   registers, and feeds mfma_32x32x16_bf16(a,a,acc). No Fb LDS round-trip.
//   4 samples/wave processed with a 2-deep ping-pong prefetch (vv[2][8]).
//   dense row 26 comes from a cooperatively precomputed Db[32][64] table.
//   dense_out segment lookup: ballot popcount (2 ballots) instead of a
//   7-deep dependent-LDS binary search.
// Phase 2: top GEMM M=32, wave w covers n-slice [w*32, w*32+32); A from LDS
//   Cs, B straight from global wt1t (L2-resident). Epilogue relu+Wt2 dot,
//   butterfly-reduce over n within wave -> partial_s[w][32].
// Phase 3: sum 8 wave partials + bt2 -> out[32].
// ---------------------------------------------------------------------------
__global__ __launch_bounds__(512, 4) void k1_fused(
    const int* __restrict__ x_cat, const float* __restrict__ price,
    const float* __restrict__ emb, const float* __restrict__ Wp,
    const float* __restrict__ bp_, const float* __restrict__ bps_g,
    const float* __restrict__ PQ, const short* __restrict__ wt1t,
    const float* __restrict__ bt1, const float* __restrict__ Wt2,
    const float* __restrict__ bt2, float* __restrict__ out) {
  __shared__ __align__(16) short Cs[32][CS_STRIDE];
  __shared__ __align__(16) short Db[32][64];
  __shared__ float partial_s[8][32];
  const int tid = threadIdx.x, lane = tid & 63, w = tid >> 6;
  const int s0 = blockIdx.x * 32;

  // dense feature rows (pre-ReLU dense_embed) for all 32 samples -> Db
  for (int i = tid; i < 2048; i += 512) {
    int sm = i >> 6, d = i & 63;
    Db[sm][d] = f2bf(fmaf(price[s0 + sm], Wp[d], bp_[d]));
  }

  const int row = lane & 31, kh = lane >> 5;
  const int koff = kh * 8;
  // breakpoints for ballot-based lower_bound (128 entries over 64 lanes x2)
  const float blo = bps_g[lane], bhi = bps_g[64 + lane];

  const int sb = s0 + w * 4;
  const bool gat = (row < NUM_FIELDS);
  int4 idx4 = make_int4(0, 0, 0, 0);
  if (gat) idx4 = *(const int4*)&x_cat[(size_t)row * BATCH + sb];
  const float4 pr4 = *(const float4*)&price[sb];
  const int   idxs[4] = {idx4.x, idx4.y, idx4.z, idx4.w};
  const float prs[4]  = {pr4.x, pr4.y, pr4.z, pr4.w};

  __syncthreads();   // Db ready

  // ---- phase 1: 4 samples per wave, 2-deep ping-pong prefetch ----
  float4 vv[2][8];
  if (gat) {
    const float* rb = emb + ((size_t)row * VOCAB + idxs[0]) * 64 + koff;
    #pragma unroll
    for (int q = 0; q < 4; ++q) {
      vv[0][2 * q]     = *(const float4*)(rb + 16 * q);
      vv[0][2 * q + 1] = *(const float4*)(rb + 16 * q + 4);
    }
  }
  #pragma unroll
  for (int it = 0; it < 4; ++it) {
    const int cur = it & 1, nxt = cur ^ 1;
    if (it < 3 && gat) {   // issue next sample's gathers before this compute
      const float* rb = emb + ((size_t)row * VOCAB + idxs[it + 1]) * 64 + koff;
      #pragma unroll
      for (int q = 0; q < 4; ++q) {
        vv[nxt][2 * q]     = *(const float4*)(rb + 16 * q);
        vv[nxt][2 * q + 1] = *(const float4*)(rb + 16 * q + 4);
      }
    }
    const int sm = w * 4 + it;
    bf16x8_t a[4];
    if (gat) {
      #pragma unroll
      for (int q = 0; q < 4; ++q) {
        const float4 x = vv[cur][2 * q], y = vv[cur][2 * q + 1];
        bf16x8_t t;
        t[0] = f2bf(x.x); t[1] = f2bf(x.y); t[2] = f2bf(x.z); t[3] = f2bf(x.w);
        t[4] = f2bf(y.x); t[5] = f2bf(y.y); t[6] = f2bf(y.z); t[7] = f2bf(y.w);
        a[q] = t;
      }
    } else if (row == 26) {
      #pragma unroll
      for (int q = 0; q < 4; ++q)
        a[q] = *(const bf16x8_t*)&Db[sm][16 * q + koff];
    } else {
      #pragma unroll
      for (int q = 0; q < 4; ++q)
        a[q] = (bf16x8_t){0, 0, 0, 0, 0, 0, 0, 0};
    }
    f32x16_t acc = {0.f,0.f,0.f,0.f,0.f,0.f,0.f,0.f,0.f,0.f,0.f,0.f,0.f,0.f,0.f,0.f};
    acc = __builtin_amdgcn_mfma_f32_32x32x16_bf16(a[0], a[0], acc, 0, 0, 0);
    acc = __builtin_amdgcn_mfma_f32_32x32x16_bf16(a[1], a[1], acc, 0, 0, 0);
    acc = __builtin_amdgcn_mfma_f32_32x32x16_bf16(a[2], a[2], acc, 0, 0, 0);
    acc = __builtin_amdgcn_mfma_f32_32x32x16_bf16(a[3], a[3], acc, 0, 0, 0);
    // dense_out via piecewise table; lower_bound by ballot popcount
    const float pr = prs[it];
    const int lo = __popcll(__ballot(blo < pr)) + __popcll(__ballot(bhi < pr));
    float dv = fmaf(pr, PQ[lo * 64 + lane], PQ[129 * 64 + lo * 64 + lane]);
    dv = fmaxf(dv, 0.f);
    Cs[sm][351 + lane] = f2bf(dv);
    if (lane == 0) Cs[sm][415] = 0;
    // scatter upper-tri interactions (C/D: col=lane&31, m=(r&3)+8*(r>>2)+4*kh)
    const int jc = row, rh = kh * 4;
    #pragma unroll
    for (int reg = 0; reg < 16; ++reg) {
      int i = (reg & 3) + 8 * (reg >> 2) + rh;
      if (i < jc && jc < 27) {
        int p = 26 * i - (i * (i - 1)) / 2 + (jc - i - 1);
        Cs[sm][p] = f2bf(acc[reg]);
      }
    }
  }
  __syncthreads();   // Cs complete
  // ---- phase 2: top GEMM, M=32 (samples), wave n-slice of 32 ----
  const int n0 = w * 32;
  const short* bp0 = wt1t + (size_t)(n0 + row) * CK + koff;
  f32x16_t tacc = {0.f,0.f,0.f,0.f,0.f,0.f,0.f,0.f,0.f,0.f,0.f,0.f,0.f,0.f,0.f,0.f};
  #pragma unroll
  for (int k0 = 0; k0 < CK; k0 += 16) {
    bf16x8_t aa = *(const bf16x8_t*)&Cs[row][k0 + koff];
    bf16x8_t bb = *(const bf16x8_t*)(bp0 + k0);
    tacc = __builtin_amdgcn_mfma_f32_32x32x16_bf16(aa, bb, tacc, 0, 0, 0);
  }
  const int n = n0 + row;
  const float bt1v = bt1[n], w2v = Wt2[n];
  float ps[16];
  #pragma unroll
  for (int r = 0; r < 16; ++r) ps[r] = fmaxf(tacc[r] + bt1v, 0.f) * w2v;
  #pragma unroll
  for (int d = 1; d <= 16; d <<= 1) {
    #pragma unroll
    for (int r = 0; r < 16; ++r) ps[r] += __shfl_xor(ps[r], d, 64);
  }
  if (row == 0) {
    #pragma unroll
    for (int r = 0; r < 16; ++r)
      partial_s[w][(r & 3) + 8 * (r >> 2) + 4 * kh] = ps[r];
  }
  __syncthreads();
  // ---- phase 3 ----
  if (tid < 32) {
    float ssum = bt2[0];
    #pragma unroll
    for (int ww = 0; ww < 8; ++ww) ssum += partial_s[ww][tid];
    out[blockIdx.x * 32 + tid] = ssum;
  }
}

// ---------------------------------------------------------------------------
extern "C" void kernel_launch(void* const* d_in, const int* in_sizes, int n_in,
                              void* d_out, int out_size, void* d_ws, size_t ws_size,
                              hipStream_t stream) {
  const int*   x_cat = (const int*)d_in[0];
  const float* price = (const float*)d_in[1];
  const float* emb   = (const float*)d_in[2];
  const float* Wp    = (const float*)d_in[3];
  const float* bp    = (const float*)d_in[4];
  const float* W1    = (const float*)d_in[5];
  const float* b1    = (const float*)d_in[6];
  const float* W2    = (const float*)d_in[7];
  const float* b2    = (const float*)d_in[8];
  const float* Wt1   = (const float*)d_in[9];
  const float* bt1   = (const float*)d_in[10];
  const float* Wt2   = (const float*)d_in[11];
  const float* bt2   = (const float*)d_in[12];
  float* out = (float*)d_out;

  // ws layout: PQ[2*129*64] f32 | bps[128] f32 | wt1t bf16[256][416]. ~280 KB.
  float* ws   = (float*)d_ws;
  float* PQ   = ws;
  float* bps  = ws + 16512;
  short* wt1t = (short*)(ws + 16640);

  k0_prep <<<dim3(257), dim3(128), 0, stream>>>(Wp, bp, W1, b1, W2, b2, Wt1, bps, PQ, wt1t);
  k1_fused<<<dim3(BATCH / 32), dim3(512), 0, stream>>>(x_cat, price, emb, Wp, bp,
                                                       bps, PQ, wt1t, bt1, Wt2, bt2, out);
}